// Round 7
// baseline (24.762 us; speedup 1.0000x reference)
//
#include <hip/hip_runtime.h>
#include <hip/hip_bf16.h>

// Problem dims (fixed): n=128, d=256, ic=16, oc=16, r=10
// x:   [n, d, ic, r]  = 5,242,880 f32
// w:   [d, ic, oc, r] =   655,360 f32   (r innermost)
// out: [n, d, oc, r]  = 5,242,880 f32
//
// out[n,d,oc,r] = log( sum_ic exp(x)*exp(w) ) - log( sum_ic exp(w) )
// |x|,|w| <~ 5.5 so unnormalized exp is safe; exp() stored bf16 in LDS
// (rel err 0.4% -> log abs err ~0.01, threshold 7.4e-2).
//
// v7: 2048 blocks x 320 threads; block = (d, 16-n chunk) -> 6 blocks/CU
// co-resident + backfill (v5/v6 had exactly 4/CU: barrier lockstep, no
// overlap). exs rows indexed by icr (bank shift 10/row kills the r-collision).
// Compute: 160 threads, 4n x 4oc x r tile (v5-proven). Epilogue: v5-proven
// stride-164 f32 res (v6's 64-float rows were the corruption bug).

#define EROW 20    // exs row stride (bf16)
#define WROW 20    // wes row stride (bf16)
#define RSP  164   // res row stride (f32), 656B: 16B-aligned, 4-bank row shift

__global__ __launch_bounds__(320, 6) void fused_lse_kernel(const float* __restrict__ x,
                                                           const float* __restrict__ w,
                                                           float* __restrict__ out) {
    __shared__ __align__(16) __hip_bfloat16 exs[160 * EROW];  // 6.25 KB [icr][colswz(n)]
    __shared__ __align__(16) __hip_bfloat16 wes[160 * WROW];  // 6.25 KB [icr][oc]
    __shared__ float lcs[160];                                // 0.64 KB
    __shared__ __align__(16) float res[16 * RSP];             // 10.5 KB

    const int tid    = threadIdx.x;
    const int d      = blockIdx.x & 255;
    const int n_base = (blockIdx.x >> 8) << 4;   // 8 chunks of 16 n

    // ---- stage exp(w[d]) -> wes[ic*10+r][oc] : 8 elems/thread --------------
    {
        const float4* wg = reinterpret_cast<const float4*>(w + d * 2560);
        float4 a = wg[tid * 2];
        float4 b = wg[tid * 2 + 1];
        float vals[8] = {a.x, a.y, a.z, a.w, b.x, b.y, b.z, b.w};
        const int base = tid * 8;
#pragma unroll
        for (int k = 0; k < 8; ++k) {
            const int off = base + k;
            const int ic  = off / 160;
            const int ocr = off - ic * 160;
            const int oc  = ocr / 10;
            const int r   = ocr - oc * 10;
            wes[(ic * 10 + r) * WROW + oc] = __float2bfloat16(__expf(vals[k]));
        }
    }

    // ---- stage exp(x) -> exs[icr][col] : 8 elems/thread ---------------------
    // col(n) = ((n>>2) ^ ((icr>>3)&3))*4 + (n&3); writer's icr>>3 == seg8.
    {
        const int n_l  = tid / 20;               // 0..15
        const int seg8 = tid % 20;               // 0..19
        const float* xg = x + ((n_base + n_l) * 256 + d) * 160 + seg8 * 8;
        float4 v0 = *reinterpret_cast<const float4*>(xg);
        float4 v1 = *reinterpret_cast<const float4*>(xg + 4);
        float vals[8] = {v0.x, v0.y, v0.z, v0.w, v1.x, v1.y, v1.z, v1.w};
        const int col = (((n_l >> 2) ^ (seg8 & 3)) << 2) + (n_l & 3);
#pragma unroll
        for (int k = 0; k < 8; ++k) {
            const int icr = seg8 * 8 + k;        // = ic*10 + r
            exs[icr * EROW + col] = __float2bfloat16(__expf(vals[k]));
        }
    }
    __syncthreads();

    // ---- lcs[oc*10+r] = log( sum_ic wes[icr][oc] ) --------------------------
    if (tid < 160) {
        const int oc = tid / 10, rr = tid - (tid / 10) * 10;
        float s = 0.f;
#pragma unroll
        for (int ic = 0; ic < 16; ++ic)
            s += __bfloat162float(wes[(ic * 10 + rr) * WROW + oc]);
        lcs[tid] = __logf(s);
    }

    // ---- compute (tid<160): thread = (r, g, oc4), tile 4n x 4oc -------------
    const int r   = tid >> 4;          // 0..9
    const int g   = (tid >> 2) & 3;    // 0..3 -> n0 = 4g
    const int oc4 = tid & 3;           // 0..3 -> oc0 = 4*oc4
    const int n0  = g << 2;
    const int oc0 = oc4 << 2;

    float acc[4][4] = {{0.f}};
    if (tid < 160) {
#pragma unroll
        for (int ic = 0; ic < 16; ++ic) {
            const int icr = ic * 10 + r;
            const int qs  = g ^ ((icr >> 3) & 3);
            const uint2 eu = *reinterpret_cast<const uint2*>(&exs[icr * EROW + (qs << 2)]);
            const uint2 wu = *reinterpret_cast<const uint2*>(&wes[icr * WROW + (oc4 << 2)]);
            const float e0 = __uint_as_float(eu.x << 16);
            const float e1 = __uint_as_float(eu.x & 0xFFFF0000u);
            const float e2 = __uint_as_float(eu.y << 16);
            const float e3 = __uint_as_float(eu.y & 0xFFFF0000u);
            const float w0 = __uint_as_float(wu.x << 16);
            const float w1 = __uint_as_float(wu.x & 0xFFFF0000u);
            const float w2 = __uint_as_float(wu.y << 16);
            const float w3 = __uint_as_float(wu.y & 0xFFFF0000u);
            acc[0][0] = fmaf(e0, w0, acc[0][0]);
            acc[0][1] = fmaf(e0, w1, acc[0][1]);
            acc[0][2] = fmaf(e0, w2, acc[0][2]);
            acc[0][3] = fmaf(e0, w3, acc[0][3]);
            acc[1][0] = fmaf(e1, w0, acc[1][0]);
            acc[1][1] = fmaf(e1, w1, acc[1][1]);
            acc[1][2] = fmaf(e1, w2, acc[1][2]);
            acc[1][3] = fmaf(e1, w3, acc[1][3]);
            acc[2][0] = fmaf(e2, w0, acc[2][0]);
            acc[2][1] = fmaf(e2, w1, acc[2][1]);
            acc[2][2] = fmaf(e2, w2, acc[2][2]);
            acc[2][3] = fmaf(e2, w3, acc[2][3]);
            acc[3][0] = fmaf(e3, w0, acc[3][0]);
            acc[3][1] = fmaf(e3, w1, acc[3][1]);
            acc[3][2] = fmaf(e3, w2, acc[3][2]);
            acc[3][3] = fmaf(e3, w3, acc[3][3]);
        }
    }
    __syncthreads();   // lcs complete; exs/wes reads done

    // ---- epilogue write (tid<160): v5-proven res layout ---------------------
    if (tid < 160) {
        float lc[4];
#pragma unroll
        for (int j = 0; j < 4; ++j) lc[j] = lcs[(oc0 + j) * 10 + r];
#pragma unroll
        for (int i = 0; i < 4; ++i)
#pragma unroll
            for (int j = 0; j < 4; ++j)
                res[(n0 + i) * RSP + (oc0 + j) * 10 + r] = __logf(acc[i][j]) - lc[j];
    }
    __syncthreads();

    // ---- coalesced store (all 320): 8 floats/thread -------------------------
    {
        const int n2  = tid / 20;                // 0..15
        const int sg8 = tid % 20;                // 0..19
        const float* rp = res + n2 * RSP + sg8 * 8;
        float4 o0 = *reinterpret_cast<const float4*>(rp);
        float4 o1 = *reinterpret_cast<const float4*>(rp + 4);
        float* og = out + ((n_base + n2) * 256 + d) * 160 + sg8 * 8;
        *reinterpret_cast<float4*>(og)     = o0;
        *reinterpret_cast<float4*>(og + 4) = o1;
    }
}

extern "C" void kernel_launch(void* const* d_in, const int* in_sizes, int n_in,
                              void* d_out, int out_size, void* d_ws, size_t ws_size,
                              hipStream_t stream) {
    const float* x = (const float*)d_in[0];
    const float* w = (const float*)d_in[1];
    float* out = (float*)d_out;

    // grid = (nc:8) * (d:256); block covers 16 n x 1 d, all (oc, r)
    fused_lse_kernel<<<2048, 320, 0, stream>>>(x, w, out);
}

// Round 8
// 18.230 us; speedup vs baseline: 1.3583x; 1.3583x over previous
//
#include <hip/hip_runtime.h>
#include <hip/hip_bf16.h>

// Problem dims (fixed): n=128, d=256, ic=16, oc=16, r=10
// x:   [n, d, ic, r]  = 5,242,880 f32
// w:   [d, ic, oc, r] =   655,360 f32   (r innermost)
// out: [n, d, oc, r]  = 5,242,880 f32
//
// out[n,d,oc,r] = log( sum_ic exp(x)*exp(w) ) - log( sum_ic exp(w) )
// |x|,|w| <~ 5.5 so unnormalized exp is safe; LDS operands bf16
// (rel err 0.4% -> log abs err ~0.01; measured absmax 0.0156 << 7.4e-2).
//
// v8: block = (d, 32n) as TWO pipelined 16n chunks, 320 threads, all
// active in every phase. All 6 global loads issue in P1 (regs); chunk1's
// stage runs after chunk0's compute -> its HBM latency hides under
// compute; chunk0's stores overlap chunk1's compute. Targets the ~36%
// HBM duty cycle of v5's lockstep phases.

#define EROW 20    // exs row stride (bf16)
#define WROW 20    // wes row stride (bf16)
#define RSP  164   // res row stride (f32): rows never overlap, 16B-aligned

__device__ __forceinline__ void stage_x_chunk(__hip_bfloat16* exs, const float4& a,
                                              const float4& b, int seg8, int colw) {
    float vals[8] = {a.x, a.y, a.z, a.w, b.x, b.y, b.z, b.w};
#pragma unroll
    for (int k = 0; k < 8; ++k)
        exs[(seg8 * 8 + k) * EROW + colw] = __float2bfloat16(__expf(vals[k]));
}

__device__ __forceinline__ void compute_chunk(const __hip_bfloat16* exs,
                                              const __hip_bfloat16* wes,
                                              int r, int ng, int oc4, float acc[2][4]) {
#pragma unroll
    for (int i = 0; i < 2; ++i)
#pragma unroll
        for (int j = 0; j < 4; ++j) acc[i][j] = 0.f;
#pragma unroll
    for (int ic = 0; ic < 16; ++ic) {
        const int icr = ic * 10 + r;
        // col of n0=2*ng: ((n0>>2) ^ ((icr>>3)&3))*4 + (n0&3); b32 -> n0,n0+1
        const int cb = (((ng >> 1) ^ ((icr >> 3) & 3)) << 2) + ((ng & 1) << 1);
        const unsigned eu = *reinterpret_cast<const unsigned*>(&exs[icr * EROW + cb]);
        const uint2 wu = *reinterpret_cast<const uint2*>(&wes[icr * WROW + (oc4 << 2)]);
        const float e0 = __uint_as_float(eu << 16);
        const float e1 = __uint_as_float(eu & 0xFFFF0000u);
        const float w0 = __uint_as_float(wu.x << 16);
        const float w1 = __uint_as_float(wu.x & 0xFFFF0000u);
        const float w2 = __uint_as_float(wu.y << 16);
        const float w3 = __uint_as_float(wu.y & 0xFFFF0000u);
        acc[0][0] = fmaf(e0, w0, acc[0][0]);
        acc[0][1] = fmaf(e0, w1, acc[0][1]);
        acc[0][2] = fmaf(e0, w2, acc[0][2]);
        acc[0][3] = fmaf(e0, w3, acc[0][3]);
        acc[1][0] = fmaf(e1, w0, acc[1][0]);
        acc[1][1] = fmaf(e1, w1, acc[1][1]);
        acc[1][2] = fmaf(e1, w2, acc[1][2]);
        acc[1][3] = fmaf(e1, w3, acc[1][3]);
    }
}

__device__ __forceinline__ void epilogue_chunk(float* res, const float* lcs,
                                               int r, int ng, int oc4, float acc[2][4]) {
#pragma unroll
    for (int j = 0; j < 4; ++j) {
        const int ocr = ((oc4 << 2) + j) * 10 + r;
        const float lcj = lcs[ocr];
#pragma unroll
        for (int i = 0; i < 2; ++i) {
            const int n = (ng << 1) + i;                 // block-local row 0..15
            const int q = (ocr >> 2) ^ (n & 7);          // quad swizzle (bijective)
            res[n * RSP + (q << 2) + (ocr & 3)] = __logf(acc[i][j]) - lcj;
        }
    }
}

__device__ __forceinline__ void store_chunk(const float* res, float* __restrict__ out,
                                            int nbase, int d, int n_l, int seg8) {
    const int f = n_l & 7;
    const float4 v0 = *reinterpret_cast<const float4*>(&res[n_l * RSP + ((((seg8 << 1) | 0) ^ f) << 2)]);
    const float4 v1 = *reinterpret_cast<const float4*>(&res[n_l * RSP + ((((seg8 << 1) | 1) ^ f) << 2)]);
    float* og = out + ((nbase + n_l) * 256 + d) * 160 + seg8 * 8;
    *reinterpret_cast<float4*>(og)     = v0;
    *reinterpret_cast<float4*>(og + 4) = v1;
}

__global__ __launch_bounds__(320, 5) void fused_lse_kernel(const float* __restrict__ x,
                                                           const float* __restrict__ w,
                                                           float* __restrict__ out) {
    __shared__ __align__(16) __hip_bfloat16 exs[160 * EROW];  // 6.25 KB
    __shared__ __align__(16) __hip_bfloat16 wes[160 * WROW];  // 6.25 KB
    __shared__ float lcs[160];                                // 0.64 KB
    __shared__ __align__(16) float res[16 * RSP];             // 10.5 KB

    const int tid     = threadIdx.x;
    const int d       = blockIdx.x & 255;
    const int n_super = (blockIdx.x >> 8) << 5;   // 4 supers of 32 n

    const int n_l  = tid / 20;    // 0..15
    const int seg8 = tid % 20;    // 0..19
    const int colw = (((n_l >> 2) ^ (seg8 & 3)) << 2) + (n_l & 3);

    // ---- P1: issue ALL global loads, then stage w + chunk0 ------------------
    const float* xg0 = x + ((n_super + n_l) * 256 + d) * 160 + seg8 * 8;
    const float* xg1 = x + ((n_super + 16 + n_l) * 256 + d) * 160 + seg8 * 8;
    const float4* wg = reinterpret_cast<const float4*>(w + d * 2560);

    const float4 xa0 = *reinterpret_cast<const float4*>(xg0);
    const float4 xb0 = *reinterpret_cast<const float4*>(xg0 + 4);
    const float4 wa  = wg[tid * 2];
    const float4 wb  = wg[tid * 2 + 1];
    const float4 xa1 = *reinterpret_cast<const float4*>(xg1);
    const float4 xb1 = *reinterpret_cast<const float4*>(xg1 + 4);

    {   // stage exp(w) -> wes[ic*10+r][oc]
        float vals[8] = {wa.x, wa.y, wa.z, wa.w, wb.x, wb.y, wb.z, wb.w};
        const int base = tid * 8;
#pragma unroll
        for (int k = 0; k < 8; ++k) {
            const int off = base + k;
            const int ic  = off / 160;
            const int ocr = off - ic * 160;
            const int oc  = ocr / 10;
            const int r   = ocr - oc * 10;
            wes[(ic * 10 + r) * WROW + oc] = __float2bfloat16(__expf(vals[k]));
        }
    }
    stage_x_chunk(exs, xa0, xb0, seg8, colw);
    __syncthreads();

    // ---- P2: lcs + compute chunk0 -------------------------------------------
    if (tid < 160) {
        const int oc = tid / 10, rr = tid - (tid / 10) * 10;
        float s = 0.f;
#pragma unroll
        for (int ic = 0; ic < 16; ++ic)
            s += __bfloat162float(wes[(ic * 10 + rr) * WROW + oc]);
        lcs[tid] = __logf(s);
    }

    const int r   = tid >> 5;        // 0..9
    const int ng  = (tid >> 2) & 7;  // 0..7  (n0 = 2*ng)
    const int oc4 = tid & 3;         // 0..3  (oc0 = 4*oc4)

    float acc[2][4];
    compute_chunk(exs, wes, r, ng, oc4, acc);
    __syncthreads();

    // ---- P3: stage chunk1 (regs already loaded) + epilogue chunk0 -----------
    stage_x_chunk(exs, xa1, xb1, seg8, colw);
    epilogue_chunk(res, lcs, r, ng, oc4, acc);
    __syncthreads();

    // ---- P4: store chunk0 (overlaps) + compute chunk1 -----------------------
    store_chunk(res, out, n_super, d, n_l, seg8);
    compute_chunk(exs, wes, r, ng, oc4, acc);
    __syncthreads();

    // ---- P5: epilogue chunk1 ------------------------------------------------
    epilogue_chunk(res, lcs, r, ng, oc4, acc);
    __syncthreads();

    // ---- P6: store chunk1 ---------------------------------------------------
    store_chunk(res, out, n_super + 16, d, n_l, seg8);
}

extern "C" void kernel_launch(void* const* d_in, const int* in_sizes, int n_in,
                              void* d_out, int out_size, void* d_ws, size_t ws_size,
                              hipStream_t stream) {
    const float* x = (const float*)d_in[0];
    const float* w = (const float*)d_in[1];
    float* out = (float*)d_out;

    // grid = (4 n-supers) * (256 d); block covers 32 n x 1 d as 2 chunks
    fused_lse_kernel<<<1024, 320, 0, stream>>>(x, w, out);
}